// Round 7
// baseline (593.672 us; speedup 1.0000x reference)
//
#include <hip/hip_runtime.h>

#define N_NODES 50000
#define N_EDGES 800000
#define ET (N_EDGES + N_NODES)   // 850000 incl. self loops
#define HEADS 8
#define NPAD 50048               // 782 blocks * 64 nodes
#define SCAN_NB 196              // ceil(50000/256)
#define LSTRIDE 1028             // LDS row stride (fp16) for the fused epilogue

typedef __attribute__((ext_vector_type(8))) _Float16 half8;
typedef __attribute__((ext_vector_type(2))) _Float16 half2v;
typedef __attribute__((ext_vector_type(4))) float f32x4;

// ---------- edge-index layout detection (int32 vs int64 storage) ----------
__global__ void k_detect(const int* __restrict__ ei, int* __restrict__ flag){
  if (blockIdx.x == 0 && threadIdx.x == 0){
    int zeros = 0;
    for (int i = 0; i < 64; i++){
      if (ei[2*i + 1] == 0) zeros++;
    }
    *flag = (zeros >= 60) ? 1 : 0;   // 1 => int64 little-endian layout
  }
}

__device__ __forceinline__ int edge_src(const int* ei, int e, int is64){
  if (e >= N_EDGES) return e - N_EDGES;          // self loop
  return is64 ? ei[2*e] : ei[e];
}
__device__ __forceinline__ int edge_dst(const int* ei, int e, int is64){
  if (e >= N_EDGES) return e - N_EDGES;          // self loop
  return is64 ? ei[2*(N_EDGES + e)] : ei[N_EDGES + e];
}

// ---------------- CSR build ----------------
__global__ void k_zero3(int* __restrict__ a, int* __restrict__ b,
                        int* __restrict__ hist){
  int i = blockIdx.x*blockDim.x + threadIdx.x;
  if (i < N_NODES){ a[i] = 0; b[i] = 0; }
  if (i < 256) hist[i] = 0;
}

__global__ void k_degree(const int* __restrict__ ei, int* __restrict__ deg,
                         const int* __restrict__ flag){
  int e = blockIdx.x*blockDim.x + threadIdx.x;
  if (e >= ET) return;
  int is64 = *flag;
  int d = edge_dst(ei, e, is64);
  atomicAdd(&deg[d], 1);
}

// ---- 3-stage scan ----
__global__ void k_scan_part(const int* __restrict__ deg, int* __restrict__ loc,
                            int* __restrict__ part){
  __shared__ int lds[256];
  int t = threadIdx.x, i = blockIdx.x*256 + t;
  int v = (i < N_NODES) ? deg[i] : 0;
  lds[t] = v;
  __syncthreads();
  for (int off = 1; off < 256; off <<= 1){
    int x = (t >= off) ? lds[t - off] : 0;
    __syncthreads();
    lds[t] += x;
    __syncthreads();
  }
  if (i < N_NODES) loc[i] = lds[t] - v;          // local exclusive
  if (t == 255) part[blockIdx.x] = lds[255];
}

__global__ void k_scan_carry(int* __restrict__ part, int* __restrict__ carry){
  __shared__ int lds[256];
  int t = threadIdx.x;
  int v = (t < SCAN_NB) ? part[t] : 0;
  lds[t] = v;
  __syncthreads();
  for (int off = 1; off < 256; off <<= 1){
    int x = (t >= off) ? lds[t - off] : 0;
    __syncthreads();
    lds[t] += x;
    __syncthreads();
  }
  if (t < SCAN_NB) carry[t] = lds[t] - v;        // exclusive over blocks
}

__global__ void k_scan_add(const int* __restrict__ loc, const int* __restrict__ carry,
                           int* __restrict__ row_ptr){
  int i = blockIdx.x*blockDim.x + threadIdx.x;
  if (i < N_NODES) row_ptr[i] = loc[i] + carry[i >> 8];
  if (i == 0) row_ptr[N_NODES] = ET;
}

__global__ void k_fill(const int* __restrict__ ei, const int* __restrict__ row_ptr,
                       int* __restrict__ cnt, int* __restrict__ col,
                       const int* __restrict__ flag){
  int e = blockIdx.x*blockDim.x + threadIdx.x;
  if (e >= ET) return;
  int is64 = *flag;
  int s = edge_src(ei, e, is64);
  int d = edge_dst(ei, e, is64);
  int pos = atomicAdd(&cnt[d], 1);
  col[row_ptr[d] + pos] = s;
}

// ---- degree counting sort -> perm (wave/block load balance) ----
__global__ void k_hist(const int* __restrict__ deg, int* __restrict__ hist){
  __shared__ int lh[256];
  int t = threadIdx.x;
  lh[t] = 0;
  __syncthreads();
  int i = blockIdx.x*256 + t;
  if (i < N_NODES){
    int d = deg[i]; if (d > 255) d = 255;
    atomicAdd(&lh[d], 1);
  }
  __syncthreads();
  if (lh[t]) atomicAdd(&hist[t], lh[t]);
}

__global__ void k_binscan(const int* __restrict__ hist, int* __restrict__ binoff){
  __shared__ int lds[256];
  int t = threadIdx.x;
  int v = hist[t];
  lds[t] = v;
  __syncthreads();
  for (int off = 1; off < 256; off <<= 1){
    int x = (t >= off) ? lds[t - off] : 0;
    __syncthreads();
    lds[t] += x;
    __syncthreads();
  }
  binoff[t] = lds[t] - v;   // exclusive
}

__global__ void k_permfill(const int* __restrict__ deg, int* __restrict__ binoff,
                           int* __restrict__ perm){
  int i = blockIdx.x*blockDim.x + threadIdx.x;
  if (i >= N_NODES) return;
  int d = deg[i]; if (d > 255) d = 255;
  int pos = atomicAdd(&binoff[d], 1);
  perm[pos] = i;
}

// ---------------- weight prep ----------------
// wtilde[h*128+k] = sum_d W2[k, h*64+d] * att[h,d]
__global__ void k_wtilde(const float* __restrict__ W2, const float* __restrict__ as2,
                         const float* __restrict__ ad2,
                         float* __restrict__ ws2, float* __restrict__ wd2){
  int t = blockIdx.x*blockDim.x + threadIdx.x;
  if (t >= 1024) return;
  int k = t >> 3, h = t & 7;
  float s = 0.f, d = 0.f;
  for (int dd = 0; dd < 64; dd++){
    float w = W2[k*512 + h*64 + dd];
    s += w * as2[h*64 + dd];
    d += w * ad2[h*64 + dd];
  }
  ws2[h*128 + k] = s;
  wd2[h*128 + k] = d;
}

// W1 fp16 B-fragments for mfma_f32_16x16x32_f16: K=128 (kt 0..3), Ncols=128 (nt 0..7)
__global__ void k_w1pack(const float* __restrict__ W1, _Float16* __restrict__ Bp1){
  int t = blockIdx.x*blockDim.x + threadIdx.x;
  if (t >= 16384) return;
  int j = t & 7, lane = (t >> 3) & 63, nt = (t >> 9) & 7, kt = t >> 12;
  int k = kt*32 + (lane >> 4)*8 + j;
  int c = nt*16 + (lane & 15);
  Bp1[t] = (_Float16)W1[k*128 + c];
}

// W2 fp16 B-fragments, 0.125 (head mean) folded; K=1024 (kt 0..31), Ncols=64 (nt 0..3)
__global__ void k_w2pack(const float* __restrict__ W2, _Float16* __restrict__ Bp){
  int t = blockIdx.x*blockDim.x + threadIdx.x;
  if (t >= 65536) return;
  int j = t & 7, lane = (t >> 3) & 63, nt = (t >> 9) & 3, kt = t >> 11;
  int k = kt*32 + (lane >> 4)*8 + j;
  int c = nt*16 + (lane & 15);
  int h = k >> 7, kk = k & 127;
  Bp[t] = (_Float16)(0.125f * W2[kk*512 + h*64 + c]);
}

// ---------------- layer 1 GEMM via MFMA: h1[N,128] = x @ W1 (fp16 out) ----------------
__global__ void __launch_bounds__(256) k_gemm1_mfma(
    const float* __restrict__ x, const _Float16* __restrict__ Bp1,
    _Float16* __restrict__ h1){
  int tid = threadIdx.x;
  int lane = tid & 63, wv = tid >> 6;
  int n0 = blockIdx.x*64 + wv*16;
  int rowA = n0 + (lane & 15);
  int koff = (lane >> 4)*8;
  const float* xr = x + (size_t)rowA*128 + koff;
  f32x4 acc[8];
  #pragma unroll
  for (int i = 0; i < 8; i++) acc[i] = (f32x4){0.f,0.f,0.f,0.f};
  bool inb = (rowA < N_NODES);
  #pragma unroll
  for (int kt = 0; kt < 4; kt++){
    half8 af;
    if (inb){
      float4 a0 = *(const float4*)(xr + kt*32);
      float4 a1 = *(const float4*)(xr + kt*32 + 4);
      af = (half8){(_Float16)a0.x,(_Float16)a0.y,(_Float16)a0.z,(_Float16)a0.w,
                   (_Float16)a1.x,(_Float16)a1.y,(_Float16)a1.z,(_Float16)a1.w};
    } else {
      af = (half8){0,0,0,0,0,0,0,0};
    }
    #pragma unroll
    for (int nt = 0; nt < 8; nt++){
      half8 bf = *(const half8*)(Bp1 + (((kt*8 + nt)*64 + lane) << 3));
      acc[nt] = __builtin_amdgcn_mfma_f32_16x16x32_f16(af, bf, acc[nt], 0, 0, 0);
    }
  }
  int r0 = n0 + (lane >> 4)*4;     // C/D: col=lane&15, row=(lane>>4)*4+reg  [m89]
  #pragma unroll
  for (int nt = 0; nt < 8; nt++){
    int c = nt*16 + (lane & 15);
    #pragma unroll
    for (int r = 0; r < 4; r++){
      int n = r0 + r;
      if (n < N_NODES) h1[(size_t)n*128 + c] = (_Float16)acc[nt][r];
    }
  }
}

// ---- alpha logits, layer 1 ----
__global__ void k_alpha1(const _Float16* __restrict__ h1, const float* __restrict__ as1,
                         const float* __restrict__ ad1,
                         float* __restrict__ als, float* __restrict__ ald){
  int t = blockIdx.x*blockDim.x + threadIdx.x;
  if (t >= N_NODES*8) return;
  int n = t >> 3, hh = t & 7;
  const half2v* hp = (const half2v*)(h1 + (size_t)n*128 + hh*16);
  float s = 0.f, d = 0.f;
  #pragma unroll
  for (int i = 0; i < 8; i++){
    half2v v = hp[i];
    float vx = (float)v.x, vy = (float)v.y;
    s += vx*as1[hh*16 + 2*i] + vy*as1[hh*16 + 2*i + 1];
    d += vx*ad1[hh*16 + 2*i] + vy*ad1[hh*16 + 2*i + 1];
  }
  als[t] = s; ald[t] = d;
}

// ---- alpha logits, layer 2 ----
__global__ void k_alpha2(const _Float16* __restrict__ hr, const float* __restrict__ ws2,
                         const float* __restrict__ wd2,
                         float* __restrict__ als, float* __restrict__ ald){
  int t = blockIdx.x*blockDim.x + threadIdx.x;
  if (t >= N_NODES*8) return;
  int n = t >> 3, hh = t & 7;
  const half2v* hp = (const half2v*)(hr + (size_t)n*128);
  float s = 0.f, d = 0.f;
  #pragma unroll 16
  for (int i = 0; i < 64; i++){
    half2v v = hp[i];
    float vx = (float)v.x, vy = (float)v.y;
    s += vx*ws2[hh*128 + 2*i] + vy*ws2[hh*128 + 2*i + 1];
    d += vx*wd2[hh*128 + 2*i] + vy*wd2[hh*128 + 2*i + 1];
  }
  als[t] = s; ald[t] = d;
}

// ===== layer 1: SINGLE-PASS softmax+aggregation =====
// Unnormalized accumulate (no max shift — logits O(10), fp32 safe), scale by 1/l
// at the end. Lane owns channels {2L,2L+1}, head hh0=L>>3; l is lane-local since
// every lane walks all edges.
__global__ void k_attn_agg1(const _Float16* __restrict__ h1,
    const float* __restrict__ als, const float* __restrict__ ald,
    const int* __restrict__ row_ptr, const int* __restrict__ col,
    const int* __restrict__ perm,
    const float* __restrict__ bias, _Float16* __restrict__ hr){
  int gid = blockIdx.x*blockDim.x + threadIdx.x;
  int wid = gid >> 6;
  int lane = threadIdx.x & 63;
  if (wid >= N_NODES) return;
  int n = perm[wid];
  int beg = row_ptr[n], end = row_ptr[n+1];
  int hh0 = lane >> 3;
  float ad = ald[n*8 + hh0];
  const half2v* h2p = (const half2v*)h1;
  float ax = 0.f, ay = 0.f, l = 0.f;
  int j = beg;
  for (; j + 7 < end; j += 8){
    int s[8]; float e[8]; half2v v[8];
    #pragma unroll
    for (int u = 0; u < 8; u++) s[u] = col[j + u];
    #pragma unroll
    for (int u = 0; u < 8; u++){
      float a = als[s[u]*8 + hh0] + ad;
      a = (a > 0.f) ? a : 0.2f*a;
      e[u] = __expf(a);
    }
    #pragma unroll
    for (int u = 0; u < 8; u++) v[u] = h2p[(size_t)s[u]*64 + lane];
    #pragma unroll
    for (int u = 0; u < 8; u++){
      l += e[u];
      ax += e[u]*(float)v[u].x;
      ay += e[u]*(float)v[u].y;
    }
  }
  for (; j < end; j++){
    int s = col[j];
    float a = als[s*8 + hh0] + ad;
    a = (a > 0.f) ? a : 0.2f*a;
    float e = __expf(a);
    half2v v = h2p[(size_t)s*64 + lane];
    l += e;
    ax += e*(float)v.x;
    ay += e*(float)v.y;
  }
  float inv = 1.f / (l + 1e-16f);
  float2 bb = ((const float2*)bias)[lane];
  float o0 = fmaxf(ax*inv + bb.x, 0.f);
  float o1 = fmaxf(ay*inv + bb.y, 0.f);
  half2v oo; oo.x = (_Float16)o0; oo.y = (_Float16)o1;
  ((half2v*)hr)[(size_t)n*64 + lane] = oo;
}

// ===== layer 2: SINGLE-PASS softmax+aggregation + fused output MFMA GEMM =====
// Block = 16 waves = 16 nodes (degree-sorted perm -> balanced barrier).
// Lane owns (head hq=lane&7, 16 channels at gq*16); fp32 unnormalized acc.
// Normalized fp16 rows -> LDS [16][1028]; waves 0..3 do the 16x64x1024 GEMM.
__global__ void __launch_bounds__(1024) k_attn_agg2(const _Float16* __restrict__ hr,
    const float* __restrict__ als, const float* __restrict__ ald,
    const int* __restrict__ row_ptr, const int* __restrict__ col,
    const int* __restrict__ perm, const _Float16* __restrict__ Bp,
    const float* __restrict__ b2, float* __restrict__ outp){
  __shared__ _Float16 at[16*LSTRIDE];
  __shared__ int nid[16];
  int tid = threadIdx.x;
  int wv = tid >> 6, lane = tid & 63;
  int n = perm[blockIdx.x*16 + wv];     // grid is exactly N/16 blocks
  if (lane == 0) nid[wv] = n;
  int beg = row_ptr[n], end = row_ptr[n+1];
  int hq = lane & 7, gq = lane >> 3;
  float ad = ald[n*8 + hq];
  float acc[16];
  #pragma unroll
  for (int i = 0; i < 16; i++) acc[i] = 0.f;
  float l = 0.f;
  int j = beg;
  for (; j + 1 < end; j += 2){
    int s0 = col[j], s1 = col[j+1];
    float a0 = als[s0*8 + hq] + ad; a0 = (a0 > 0.f) ? a0 : 0.2f*a0;
    float a1 = als[s1*8 + hq] + ad; a1 = (a1 > 0.f) ? a1 : 0.2f*a1;
    float e0 = __expf(a0), e1 = __expf(a1);
    l += e0 + e1;
    const _Float16* p0 = hr + (size_t)s0*128 + gq*16;
    const _Float16* p1 = hr + (size_t)s1*128 + gq*16;
    half8 va0 = *(const half8*)p0, vb0 = *(const half8*)(p0 + 8);
    half8 va1 = *(const half8*)p1, vb1 = *(const half8*)(p1 + 8);
    #pragma unroll
    for (int k = 0; k < 8; k++){
      acc[k]   += e0*(float)va0[k] + e1*(float)va1[k];
      acc[k+8] += e0*(float)vb0[k] + e1*(float)vb1[k];
    }
  }
  for (; j < end; j++){
    int s = col[j];
    float a = als[s*8 + hq] + ad; a = (a > 0.f) ? a : 0.2f*a;
    float e = __expf(a);
    l += e;
    const _Float16* p = hr + (size_t)s*128 + gq*16;
    half8 va = *(const half8*)p, vb = *(const half8*)(p + 8);
    #pragma unroll
    for (int k = 0; k < 8; k++){
      acc[k]   += e*(float)va[k];
      acc[k+8] += e*(float)vb[k];
    }
  }
  float inv = 1.f / (l + 1e-16f);
  _Float16* ar = at + wv*LSTRIDE + hq*128 + gq*16;
  half8 oa, ob;
  #pragma unroll
  for (int k = 0; k < 8; k++){
    oa[k] = (_Float16)(acc[k]*inv);
    ob[k] = (_Float16)(acc[k+8]*inv);
  }
  *(half8*)ar = oa;
  *(half8*)(ar + 8) = ob;
  __syncthreads();
  if (wv >= 4) return;
  // MFMA epilogue: wave wv = output tile nt; A from LDS, B from Bp (L2-hot)
  int m = lane & 15, q = lane >> 4;
  const _Float16* arow = at + m*LSTRIDE + q*8;
  f32x4 cacc = (f32x4){0.f,0.f,0.f,0.f};
  #pragma unroll 4
  for (int kt = 0; kt < 32; kt++){
    half8 af = *(const half8*)(arow + kt*32);
    half8 bf = *(const half8*)(Bp + (((kt*4 + wv)*64 + lane) << 3));
    cacc = __builtin_amdgcn_mfma_f32_16x16x32_f16(af, bf, cacc, 0, 0, 0);
  }
  int c = wv*16 + m;
  float bb = b2[c];
  #pragma unroll
  for (int r = 0; r < 4; r++){
    int row = q*4 + r;               // C/D: col=lane&15, row=(lane>>4)*4+reg [m89]
    outp[(size_t)nid[row]*64 + c] = cacc[r] + bb;
  }
}

extern "C" void kernel_launch(void* const* d_in, const int* in_sizes, int n_in,
                              void* d_out, int out_size, void* d_ws, size_t ws_size,
                              hipStream_t stream){
  const float* x   = (const float*)d_in[0];
  const int*   ei  = (const int*)d_in[1];
  const float* W1  = (const float*)d_in[2];
  const float* as1 = (const float*)d_in[3];
  const float* ad1 = (const float*)d_in[4];
  const float* b1  = (const float*)d_in[5];
  const float* W2  = (const float*)d_in[6];
  const float* as2 = (const float*)d_in[7];
  const float* ad2 = (const float*)d_in[8];
  const float* b2  = (const float*)d_in[9];
  float* outp = (float*)d_out;

  char* p = (char*)d_ws;
  auto alloc = [&](size_t bytes) -> void* {
    void* r = (void*)p;
    p += (bytes + 255) & ~(size_t)255;
    return r;
  };
  _Float16* h1  = (_Float16*)alloc((size_t)NPAD*128*2);          // [N,128] fp16
  _Float16* hr  = (_Float16*)alloc((size_t)N_NODES*128*2);       // [N,128] fp16
  float* als1 = (float*)alloc((size_t)N_NODES*8*4);
  float* ald1 = (float*)alloc((size_t)N_NODES*8*4);
  float* als2 = (float*)alloc((size_t)N_NODES*8*4);
  float* ald2 = (float*)alloc((size_t)N_NODES*8*4);
  int* row_ptr = (int*)alloc((size_t)(N_NODES+1)*4);
  int* deg  = (int*)alloc((size_t)N_NODES*4);
  int* cnt  = (int*)alloc((size_t)N_NODES*4);
  int* col  = (int*)alloc((size_t)ET*4);
  int* loc  = (int*)alloc((size_t)N_NODES*4);
  int* part = (int*)alloc(256*4);
  int* carry= (int*)alloc(256*4);
  int* flag = (int*)alloc(256);
  int* hist = (int*)alloc(256*4);
  int* binoff = (int*)alloc(256*4);
  int* perm = (int*)alloc((size_t)N_NODES*4);
  float* ws2 = (float*)alloc(1024*4);
  float* wd2 = (float*)alloc(1024*4);
  _Float16* Bp1 = (_Float16*)alloc((size_t)16384*2);
  _Float16* Bp  = (_Float16*)alloc((size_t)65536*2);

  dim3 b256(256);
  // edge-index layout probe + CSR build + degree-sort perm
  k_detect<<<1, 64, 0, stream>>>(ei, flag);
  k_zero3<<<(N_NODES+255)/256, b256, 0, stream>>>(deg, cnt, hist);
  k_degree<<<(ET+255)/256, b256, 0, stream>>>(ei, deg, flag);
  k_scan_part<<<SCAN_NB, b256, 0, stream>>>(deg, loc, part);
  k_scan_carry<<<1, b256, 0, stream>>>(part, carry);
  k_scan_add<<<SCAN_NB, b256, 0, stream>>>(loc, carry, row_ptr);
  k_fill<<<(ET+255)/256, b256, 0, stream>>>(ei, row_ptr, cnt, col, flag);
  k_hist<<<SCAN_NB, b256, 0, stream>>>(deg, hist);
  k_binscan<<<1, b256, 0, stream>>>(hist, binoff);
  k_permfill<<<SCAN_NB, b256, 0, stream>>>(deg, binoff, perm);
  // weight prep
  k_wtilde<<<4, b256, 0, stream>>>(W2, as2, ad2, ws2, wd2);
  k_w1pack<<<64, b256, 0, stream>>>(W1, Bp1);
  k_w2pack<<<256, b256, 0, stream>>>(W2, Bp);

  int nwave_blocks = (N_NODES*64 + 255)/256;   // one wave per node
  int nh_blocks = (N_NODES*8 + 255)/256;
  // layer 1
  k_gemm1_mfma<<<NPAD/64, b256, 0, stream>>>(x, Bp1, h1);
  k_alpha1<<<nh_blocks, b256, 0, stream>>>(h1, as1, ad1, als1, ald1);
  k_attn_agg1<<<nwave_blocks, b256, 0, stream>>>(h1, als1, ald1, row_ptr, col,
                                                 perm, b1, hr);
  // layer 2 (fused aggregation + output GEMM)
  k_alpha2<<<nh_blocks, b256, 0, stream>>>(hr, ws2, wd2, als2, ald2);
  k_attn_agg2<<<N_NODES/16, dim3(1024), 0, stream>>>(hr, als2, ald2, row_ptr, col,
                                                     perm, Bp, b2, outp);
}

// Round 8
// 431.951 us; speedup vs baseline: 1.3744x; 1.3744x over previous
//
#include <hip/hip_runtime.h>

#define N_NODES 50000
#define N_EDGES 800000
#define ET (N_EDGES + N_NODES)   // 850000 incl. self loops
#define HEADS 8
#define NPAD 50048               // 782 blocks * 64 nodes
#define SCAN_NB 196              // ceil(50000/256)

typedef __attribute__((ext_vector_type(8))) _Float16 half8;
typedef __attribute__((ext_vector_type(2))) _Float16 half2v;
typedef __attribute__((ext_vector_type(4))) float f32x4;

// ---------- edge-index layout detection (int32 vs int64 storage) ----------
__global__ void k_detect(const int* __restrict__ ei, int* __restrict__ flag){
  if (blockIdx.x == 0 && threadIdx.x == 0){
    int zeros = 0;
    for (int i = 0; i < 64; i++){
      if (ei[2*i + 1] == 0) zeros++;
    }
    *flag = (zeros >= 60) ? 1 : 0;   // 1 => int64 little-endian layout
  }
}

__device__ __forceinline__ int edge_src(const int* ei, int e, int is64){
  if (e >= N_EDGES) return e - N_EDGES;          // self loop
  return is64 ? ei[2*e] : ei[e];
}
__device__ __forceinline__ int edge_dst(const int* ei, int e, int is64){
  if (e >= N_EDGES) return e - N_EDGES;          // self loop
  return is64 ? ei[2*(N_EDGES + e)] : ei[N_EDGES + e];
}

// ---------------- CSR build ----------------
__global__ void k_zero2(int* __restrict__ a, int* __restrict__ b, int n){
  int i = blockIdx.x*blockDim.x + threadIdx.x;
  if (i < n){ a[i] = 0; b[i] = 0; }
}

__global__ void k_degree(const int* __restrict__ ei, int* __restrict__ deg,
                         const int* __restrict__ flag){
  int e = blockIdx.x*blockDim.x + threadIdx.x;
  if (e >= ET) return;
  int is64 = *flag;
  int d = edge_dst(ei, e, is64);
  atomicAdd(&deg[d], 1);
}

// ---- 3-stage scan ----
__global__ void k_scan_part(const int* __restrict__ deg, int* __restrict__ loc,
                            int* __restrict__ part){
  __shared__ int lds[256];
  int t = threadIdx.x, i = blockIdx.x*256 + t;
  int v = (i < N_NODES) ? deg[i] : 0;
  lds[t] = v;
  __syncthreads();
  for (int off = 1; off < 256; off <<= 1){
    int x = (t >= off) ? lds[t - off] : 0;
    __syncthreads();
    lds[t] += x;
    __syncthreads();
  }
  if (i < N_NODES) loc[i] = lds[t] - v;          // local exclusive
  if (t == 255) part[blockIdx.x] = lds[255];
}

__global__ void k_scan_carry(int* __restrict__ part, int* __restrict__ carry){
  __shared__ int lds[256];
  int t = threadIdx.x;
  int v = (t < SCAN_NB) ? part[t] : 0;
  lds[t] = v;
  __syncthreads();
  for (int off = 1; off < 256; off <<= 1){
    int x = (t >= off) ? lds[t - off] : 0;
    __syncthreads();
    lds[t] += x;
    __syncthreads();
  }
  if (t < SCAN_NB) carry[t] = lds[t] - v;        // exclusive over blocks
}

__global__ void k_scan_add(const int* __restrict__ loc, const int* __restrict__ carry,
                           int* __restrict__ row_ptr){
  int i = blockIdx.x*blockDim.x + threadIdx.x;
  if (i < N_NODES) row_ptr[i] = loc[i] + carry[i >> 8];
  if (i == 0) row_ptr[N_NODES] = ET;
}

__global__ void k_fill(const int* __restrict__ ei, const int* __restrict__ row_ptr,
                       int* __restrict__ cnt, int* __restrict__ col,
                       const int* __restrict__ flag){
  int e = blockIdx.x*blockDim.x + threadIdx.x;
  if (e >= ET) return;
  int is64 = *flag;
  int s = edge_src(ei, e, is64);
  int d = edge_dst(ei, e, is64);
  int pos = atomicAdd(&cnt[d], 1);
  col[row_ptr[d] + pos] = s;
}

// ---------------- merged weight prep (one launch) ----------------
// blocks [0,256): W2 pack; [256,320): W1 pack; [320,324): wtilde
__global__ void k_wprep(const float* __restrict__ W1, const float* __restrict__ W2,
                        const float* __restrict__ as2, const float* __restrict__ ad2,
                        _Float16* __restrict__ Bp1, _Float16* __restrict__ Bp,
                        float* __restrict__ ws2, float* __restrict__ wd2){
  int b = blockIdx.x;
  int t_ = threadIdx.x;
  if (b < 256){
    // W2 fp16 B-frags, 0.125 folded; t in [0,65536)
    int t = b*256 + t_;
    int j = t & 7, lane = (t >> 3) & 63, nt = (t >> 9) & 3, kt = t >> 11;
    int k = kt*32 + (lane >> 4)*8 + j;
    int c = nt*16 + (lane & 15);
    int h = k >> 7, kk = k & 127;
    Bp[t] = (_Float16)(0.125f * W2[kk*512 + h*64 + c]);
  } else if (b < 320){
    // W1 fp16 B-frags; t in [0,16384)
    int t = (b - 256)*256 + t_;
    int j = t & 7, lane = (t >> 3) & 63, nt = (t >> 9) & 7, kt = t >> 12;
    int k = kt*32 + (lane >> 4)*8 + j;
    int c = nt*16 + (lane & 15);
    Bp1[t] = (_Float16)W1[k*128 + c];
  } else {
    // wtilde[h*128+k]; t in [0,1024)
    int t = (b - 320)*256 + t_;
    int k = t >> 3, h = t & 7;
    float s = 0.f, d = 0.f;
    for (int dd = 0; dd < 64; dd++){
      float w = W2[k*512 + h*64 + dd];
      s += w * as2[h*64 + dd];
      d += w * ad2[h*64 + dd];
    }
    ws2[h*128 + k] = s;
    wd2[h*128 + k] = d;
  }
}

// ---------------- layer 1 GEMM via MFMA: h1[N,128] = x @ W1 (fp16 out) ----------------
__global__ void __launch_bounds__(256) k_gemm1_mfma(
    const float* __restrict__ x, const _Float16* __restrict__ Bp1,
    _Float16* __restrict__ h1){
  int tid = threadIdx.x;
  int lane = tid & 63, wv = tid >> 6;
  int n0 = blockIdx.x*64 + wv*16;
  int rowA = n0 + (lane & 15);
  int koff = (lane >> 4)*8;
  const float* xr = x + (size_t)rowA*128 + koff;
  f32x4 acc[8];
  #pragma unroll
  for (int i = 0; i < 8; i++) acc[i] = (f32x4){0.f,0.f,0.f,0.f};
  bool inb = (rowA < N_NODES);
  #pragma unroll
  for (int kt = 0; kt < 4; kt++){
    half8 af;
    if (inb){
      float4 a0 = *(const float4*)(xr + kt*32);
      float4 a1 = *(const float4*)(xr + kt*32 + 4);
      af = (half8){(_Float16)a0.x,(_Float16)a0.y,(_Float16)a0.z,(_Float16)a0.w,
                   (_Float16)a1.x,(_Float16)a1.y,(_Float16)a1.z,(_Float16)a1.w};
    } else {
      af = (half8){0,0,0,0,0,0,0,0};
    }
    #pragma unroll
    for (int nt = 0; nt < 8; nt++){
      half8 bf = *(const half8*)(Bp1 + (((kt*8 + nt)*64 + lane) << 3));
      acc[nt] = __builtin_amdgcn_mfma_f32_16x16x32_f16(af, bf, acc[nt], 0, 0, 0);
    }
  }
  int r0 = n0 + (lane >> 4)*4;     // C/D: col=lane&15, row=(lane>>4)*4+reg  [m89]
  #pragma unroll
  for (int nt = 0; nt < 8; nt++){
    int c = nt*16 + (lane & 15);
    #pragma unroll
    for (int r = 0; r < 4; r++){
      int n = r0 + r;
      if (n < N_NODES) h1[(size_t)n*128 + c] = (_Float16)acc[nt][r];
    }
  }
}

// ---- alpha logits, layer 1 ----
__global__ void k_alpha1(const _Float16* __restrict__ h1, const float* __restrict__ as1,
                         const float* __restrict__ ad1,
                         float* __restrict__ als, float* __restrict__ ald){
  int t = blockIdx.x*blockDim.x + threadIdx.x;
  if (t >= N_NODES*8) return;
  int n = t >> 3, hh = t & 7;
  const half2v* hp = (const half2v*)(h1 + (size_t)n*128 + hh*16);
  float s = 0.f, d = 0.f;
  #pragma unroll
  for (int i = 0; i < 8; i++){
    half2v v = hp[i];
    float vx = (float)v.x, vy = (float)v.y;
    s += vx*as1[hh*16 + 2*i] + vy*as1[hh*16 + 2*i + 1];
    d += vx*ad1[hh*16 + 2*i] + vy*ad1[hh*16 + 2*i + 1];
  }
  als[t] = s; ald[t] = d;
}

// ---- alpha logits, layer 2 ----
__global__ void k_alpha2(const _Float16* __restrict__ hr, const float* __restrict__ ws2,
                         const float* __restrict__ wd2,
                         float* __restrict__ als, float* __restrict__ ald){
  int t = blockIdx.x*blockDim.x + threadIdx.x;
  if (t >= N_NODES*8) return;
  int n = t >> 3, hh = t & 7;
  const half2v* hp = (const half2v*)(hr + (size_t)n*128);
  float s = 0.f, d = 0.f;
  #pragma unroll 16
  for (int i = 0; i < 64; i++){
    half2v v = hp[i];
    float vx = (float)v.x, vy = (float)v.y;
    s += vx*ws2[hh*128 + 2*i] + vy*ws2[hh*128 + 2*i + 1];
    d += vx*wd2[hh*128 + 2*i] + vy*wd2[hh*128 + 2*i + 1];
  }
  als[t] = s; ald[t] = d;
}

// ===== layer 1: SINGLE-PASS softmax+aggregation (wave per node, n = wid) =====
// Unnormalized accumulate (no max shift — logits O(10), fp32 safe), scale 1/l at
// the end. Lane owns channels {2L,2L+1}, head hh0=L>>3; l is lane-local.
__global__ void k_attn_agg1(const _Float16* __restrict__ h1,
    const float* __restrict__ als, const float* __restrict__ ald,
    const int* __restrict__ row_ptr, const int* __restrict__ col,
    const float* __restrict__ bias, _Float16* __restrict__ hr){
  int gid = blockIdx.x*blockDim.x + threadIdx.x;
  int n = gid >> 6;
  int lane = threadIdx.x & 63;
  if (n >= N_NODES) return;
  int beg = row_ptr[n], end = row_ptr[n+1];
  int hh0 = lane >> 3;
  float ad = ald[n*8 + hh0];
  const half2v* h2p = (const half2v*)h1;
  float ax = 0.f, ay = 0.f, l = 0.f;
  int j = beg;
  for (; j + 7 < end; j += 8){
    int s[8]; float e[8]; half2v v[8];
    #pragma unroll
    for (int u = 0; u < 8; u++) s[u] = col[j + u];
    #pragma unroll
    for (int u = 0; u < 8; u++){
      float a = als[s[u]*8 + hh0] + ad;
      a = (a > 0.f) ? a : 0.2f*a;
      e[u] = __expf(a);
    }
    #pragma unroll
    for (int u = 0; u < 8; u++) v[u] = h2p[(size_t)s[u]*64 + lane];
    #pragma unroll
    for (int u = 0; u < 8; u++){
      l += e[u];
      ax += e[u]*(float)v[u].x;
      ay += e[u]*(float)v[u].y;
    }
  }
  for (; j < end; j++){
    int s = col[j];
    float a = als[s*8 + hh0] + ad;
    a = (a > 0.f) ? a : 0.2f*a;
    float e = __expf(a);
    half2v v = h2p[(size_t)s*64 + lane];
    l += e;
    ax += e*(float)v.x;
    ay += e*(float)v.y;
  }
  float inv = 1.f / (l + 1e-16f);
  float2 bb = ((const float2*)bias)[lane];
  float o0 = fmaxf(ax*inv + bb.x, 0.f);
  float o1 = fmaxf(ay*inv + bb.y, 0.f);
  half2v oo; oo.x = (_Float16)o0; oo.y = (_Float16)o1;
  ((half2v*)hr)[(size_t)n*64 + lane] = oo;
}

// ===== layer 2: SINGLE-PASS softmax+aggregation -> fp16 agg[N,1024] =====
// Lane owns (head hq=lane&7, 16 channels at gq*16); fp32 unnormalized acc,
// normalize + fp16 pack in epilogue. One gather pass, no ewl.
__global__ void k_attn_agg2(const _Float16* __restrict__ hr,
    const float* __restrict__ als, const float* __restrict__ ald,
    const int* __restrict__ row_ptr, const int* __restrict__ col,
    _Float16* __restrict__ aggb){
  int gid = blockIdx.x*blockDim.x + threadIdx.x;
  int n = gid >> 6;
  int lane = threadIdx.x & 63;
  if (n >= N_NODES) return;
  int beg = row_ptr[n], end = row_ptr[n+1];
  int hq = lane & 7, gq = lane >> 3;
  float ad = ald[n*8 + hq];
  float acc[16];
  #pragma unroll
  for (int i = 0; i < 16; i++) acc[i] = 0.f;
  float l = 0.f;
  int j = beg;
  for (; j + 1 < end; j += 2){
    int s0 = col[j], s1 = col[j+1];
    float a0 = als[s0*8 + hq] + ad; a0 = (a0 > 0.f) ? a0 : 0.2f*a0;
    float a1 = als[s1*8 + hq] + ad; a1 = (a1 > 0.f) ? a1 : 0.2f*a1;
    float e0 = __expf(a0), e1 = __expf(a1);
    l += e0 + e1;
    const _Float16* p0 = hr + (size_t)s0*128 + gq*16;
    const _Float16* p1 = hr + (size_t)s1*128 + gq*16;
    half8 va0 = *(const half8*)p0, vb0 = *(const half8*)(p0 + 8);
    half8 va1 = *(const half8*)p1, vb1 = *(const half8*)(p1 + 8);
    #pragma unroll
    for (int k = 0; k < 8; k++){
      acc[k]   += e0*(float)va0[k] + e1*(float)va1[k];
      acc[k+8] += e0*(float)vb0[k] + e1*(float)vb1[k];
    }
  }
  for (; j < end; j++){
    int s = col[j];
    float a = als[s*8 + hq] + ad; a = (a > 0.f) ? a : 0.2f*a;
    float e = __expf(a);
    l += e;
    const _Float16* p = hr + (size_t)s*128 + gq*16;
    half8 va = *(const half8*)p, vb = *(const half8*)(p + 8);
    #pragma unroll
    for (int k = 0; k < 8; k++){
      acc[k]   += e*(float)va[k];
      acc[k+8] += e*(float)vb[k];
    }
  }
  float inv = 1.f / (l + 1e-16f);
  _Float16* ar = aggb + (size_t)n*1024 + hq*128 + gq*16;
  half8 oa, ob;
  #pragma unroll
  for (int k = 0; k < 8; k++){
    oa[k] = (_Float16)(acc[k]*inv);
    ob[k] = (_Float16)(acc[k+8]*inv);
  }
  *(half8*)ar = oa;
  *(half8*)(ar + 8) = ob;
}

// ------- layer-2 output GEMM via MFMA f16: out = agg[N,1024] @ Wt[1024,64] + b2 -------
__global__ void __launch_bounds__(256) k_gemm_out_mfma(
    const _Float16* __restrict__ aggb, const _Float16* __restrict__ Bp,
    const float* __restrict__ b2, float* __restrict__ outp){
  int tid = threadIdx.x;
  int lane = tid & 63, wv = tid >> 6;
  int n0 = blockIdx.x*64 + wv*16;
  int rowA = n0 + (lane & 15);
  const _Float16* arow = aggb + (size_t)rowA*1024 + (lane >> 4)*8;
  f32x4 acc[4];
  #pragma unroll
  for (int i = 0; i < 4; i++) acc[i] = (f32x4){0.f,0.f,0.f,0.f};
  for (int kt = 0; kt < 32; kt++){
    half8 af = *(const half8*)(arow + kt*32);
    #pragma unroll
    for (int nt = 0; nt < 4; nt++){
      half8 bf = *(const half8*)(Bp + (((kt*4 + nt)*64 + lane) << 3));
      acc[nt] = __builtin_amdgcn_mfma_f32_16x16x32_f16(af, bf, acc[nt], 0, 0, 0);
    }
  }
  int r0 = n0 + (lane >> 4)*4;     // C/D: col=lane&15, row=(lane>>4)*4+reg  [m89]
  #pragma unroll
  for (int nt = 0; nt < 4; nt++){
    int c = nt*16 + (lane & 15);
    float bb = b2[c];
    #pragma unroll
    for (int r = 0; r < 4; r++){
      int n = r0 + r;
      if (n < N_NODES) outp[n*64 + c] = acc[nt][r] + bb;
    }
  }
}

extern "C" void kernel_launch(void* const* d_in, const int* in_sizes, int n_in,
                              void* d_out, int out_size, void* d_ws, size_t ws_size,
                              hipStream_t stream){
  const float* x   = (const float*)d_in[0];
  const int*   ei  = (const int*)d_in[1];
  const float* W1  = (const float*)d_in[2];
  const float* as1 = (const float*)d_in[3];
  const float* ad1 = (const float*)d_in[4];
  const float* b1  = (const float*)d_in[5];
  const float* W2  = (const float*)d_in[6];
  const float* as2 = (const float*)d_in[7];
  const float* ad2 = (const float*)d_in[8];
  const float* b2  = (const float*)d_in[9];
  float* outp = (float*)d_out;

  char* p = (char*)d_ws;
  auto alloc = [&](size_t bytes) -> void* {
    void* r = (void*)p;
    p += (bytes + 255) & ~(size_t)255;
    return r;
  };
  // aggb (102.5 MB) also hosts h1 (12.8 MB) — h1 dead before k_attn_agg2 writes.
  _Float16* aggb = (_Float16*)alloc((size_t)NPAD*1024*2);
  _Float16* h1  = aggb;                                          // [N,128] fp16
  _Float16* hr  = (_Float16*)alloc((size_t)N_NODES*128*2);       // [N,128] fp16
  float* als1 = (float*)alloc((size_t)N_NODES*8*4);
  float* ald1 = (float*)alloc((size_t)N_NODES*8*4);
  float* als2 = (float*)alloc((size_t)N_NODES*8*4);
  float* ald2 = (float*)alloc((size_t)N_NODES*8*4);
  int* row_ptr = (int*)alloc((size_t)(N_NODES+1)*4);
  int* deg  = (int*)alloc((size_t)N_NODES*4);
  int* cnt  = (int*)alloc((size_t)N_NODES*4);
  int* col  = (int*)alloc((size_t)ET*4);
  int* loc  = (int*)alloc((size_t)N_NODES*4);
  int* part = (int*)alloc(256*4);
  int* carry= (int*)alloc(256*4);
  int* flag = (int*)alloc(256);
  float* ws2 = (float*)alloc(1024*4);
  float* wd2 = (float*)alloc(1024*4);
  _Float16* Bp1 = (_Float16*)alloc((size_t)16384*2);
  _Float16* Bp  = (_Float16*)alloc((size_t)65536*2);

  dim3 b256(256);
  // edge-index layout probe + CSR build
  k_detect<<<1, 64, 0, stream>>>(ei, flag);
  k_zero2<<<(N_NODES+255)/256, b256, 0, stream>>>(deg, cnt, N_NODES);
  k_degree<<<(ET+255)/256, b256, 0, stream>>>(ei, deg, flag);
  k_scan_part<<<SCAN_NB, b256, 0, stream>>>(deg, loc, part);
  k_scan_carry<<<1, b256, 0, stream>>>(part, carry);
  k_scan_add<<<SCAN_NB, b256, 0, stream>>>(loc, carry, row_ptr);
  k_fill<<<(ET+255)/256, b256, 0, stream>>>(ei, row_ptr, cnt, col, flag);
  // merged weight prep (one launch)
  k_wprep<<<324, b256, 0, stream>>>(W1, W2, as2, ad2, Bp1, Bp, ws2, wd2);

  int nwave_blocks = (N_NODES*64 + 255)/256;   // one wave per node
  int nh_blocks = (N_NODES*8 + 255)/256;
  // layer 1
  k_gemm1_mfma<<<NPAD/64, b256, 0, stream>>>(x, Bp1, h1);
  k_alpha1<<<nh_blocks, b256, 0, stream>>>(h1, as1, ad1, als1, ald1);
  k_attn_agg1<<<nwave_blocks, b256, 0, stream>>>(h1, als1, ald1, row_ptr, col,
                                                 b1, hr);
  // layer 2
  k_alpha2<<<nh_blocks, b256, 0, stream>>>(hr, ws2, wd2, als2, ald2);
  k_attn_agg2<<<nwave_blocks, b256, 0, stream>>>(hr, als2, ald2, row_ptr, col, aggb);
  k_gemm_out_mfma<<<NPAD/64, b256, 0, stream>>>(aggb, Bp, b2, outp);
}